// Round 3
// 352.959 us; speedup vs baseline: 1.0676x; 1.0676x over previous
//
#include <hip/hip_runtime.h>

typedef unsigned short u16;
typedef unsigned int u32;
typedef __bf16 bf16x8 __attribute__((ext_vector_type(8)));
typedef float f32x4 __attribute__((ext_vector_type(4)));

#if defined(__has_builtin)
#  if __has_builtin(__builtin_amdgcn_cvt_pk_bf16_f32)
#    define PK_BF16 1
#  endif
#endif

__device__ __forceinline__ u16 f2bu(float f){
  u32 u = __float_as_uint(f);
  return (u16)((u + 0x7fffu + ((u >> 16) & 1u)) >> 16);
}
__device__ __forceinline__ float b2f(u16 u){
  union { float f; u32 i; } v; v.i = ((u32)u) << 16; return v.f;
}
__device__ __forceinline__ u32 pkbf(float a, float b){
#ifdef PK_BF16
  typedef __bf16 bf16x2 __attribute__((ext_vector_type(2)));
  union { bf16x2 h; u32 u; } c;
  c.h = __builtin_amdgcn_cvt_pk_bf16_f32(a, b);
  return c.u;
#else
  return (u32)f2bu(a) | ((u32)f2bu(b) << 16);
#endif
}
// async global->LDS, 16B per lane; LDS dest = wave-uniform base + lane*16
__device__ __forceinline__ void glds16(const u16* g, u16* l){
  __builtin_amdgcn_global_load_lds(
      (const __attribute__((address_space(1))) void*)g,
      (__attribute__((address_space(3))) void*)l, 16, 0, 0);
}
__device__ __forceinline__ void glds16f(const float* g, float* l){
  __builtin_amdgcn_global_load_lds(
      (const __attribute__((address_space(1))) void*)g,
      (__attribute__((address_space(3))) void*)l, 16, 0, 0);
}

// ---------------------------------------------------------------------------
// prep_wc: Wc[384][320] bf16 = Wp + 1e-5*Wm (zero padded), bc[384] f32
// ---------------------------------------------------------------------------
__global__ __launch_bounds__(256) void prep_wc(
    const float* __restrict__ Wp, const float* __restrict__ bp,
    const float* __restrict__ Wm, const float* __restrict__ bm,
    u16* __restrict__ Wc, float* __restrict__ bc)
{
  int idx = blockIdx.x * 256 + threadIdx.x;   // bf16-pair index
  if (idx < 384 * 160) {
    int n = idx / 160, k = (idx % 160) * 2;
    float v0 = 0.f, v1 = 0.f;
    if (n < 300 && k < 300) {
      v0 = Wp[n * 300 + k]     + 1e-5f * Wm[n * 300 + k];
      v1 = Wp[n * 300 + k + 1] + 1e-5f * Wm[n * 300 + k + 1];
    }
    ((u32*)Wc)[idx] = pkbf(v0, v1);
    if (idx < 384) bc[idx] = (idx < 300) ? bp[idx] + 1e-5f * bm[idx] : 0.f;
  }
}

// ---------------------------------------------------------------------------
// prep_wv16: wv16[30000][320] bf16 copy of wv (cols 300..319 zero)
// ---------------------------------------------------------------------------
__global__ __launch_bounds__(256) void prep_wv16(
    const float* __restrict__ wv, u16* __restrict__ wv16)
{
  int idx = blockIdx.x * 256 + threadIdx.x;   // pair index
  if (idx < 30000 * 160) {
    int row = idx / 160, k = (idx % 160) * 2;
    float v0 = 0.f, v1 = 0.f;
    if (k < 300) {
      v0 = wv[(size_t)row * 300 + k];
      v1 = wv[(size_t)row * 300 + k + 1];
    }
    ((u32*)wv16)[idx] = pkbf(v0, v1);
  }
}

// ---------------------------------------------------------------------------
// prep_wf16: Wf[300][2048] f32 -> Wf16[384][2048] bf16 (rows 300..383 zero)
// ---------------------------------------------------------------------------
__global__ __launch_bounds__(256) void prep_wf16(
    const float* __restrict__ Wf, u16* __restrict__ Wf16)
{
  int i = blockIdx.x * 256 + threadIdx.x;   // pair index, 384*1024 total
  if (i < 384 * 1024) {
    int row = i >> 10, c2 = (i & 1023) * 2;
    float v0 = 0.f, v1 = 0.f;
    if (row < 300) {
      v0 = Wf[(size_t)row * 2048 + c2];
      v1 = Wf[(size_t)row * 2048 + c2 + 1];
    }
    ((u32*)Wf16)[i] = pkbf(v0, v1);
  }
}

// ---------------------------------------------------------------------------
// gemm0 fallback (no workspace): f32 sources, cvt in staging, 128x128 tile.
// ---------------------------------------------------------------------------
template <int GLDS>
__global__ __launch_bounds__(256) void gemm0_kernel(
    const float* __restrict__ A, const float* __restrict__ B,
    const u16* __restrict__ Af16, const u16* __restrict__ Bf16,
    const float* __restrict__ bias,
    const int* __restrict__ label, const float* __restrict__ wv,
    float* __restrict__ C, u16* __restrict__ kemb16)
{
  __shared__ __align__(16) u16 As[128 * 32];
  __shared__ __align__(16) u16 Bs[128 * 32];
  const int lda = 2048, K = 2048, nbn = 3, nsrc = 300;
  int t = threadIdx.x;
  int bm = (blockIdx.x / nbn) * 128;
  int bn = (blockIdx.x % nbn) * 128;
  int lane = t & 63, w = t >> 6;
  int wm = (w >> 1) * 64, wn = (w & 1) * 64;

  f32x4 acc[4][4];
  for (int i = 0; i < 4; i++)
    for (int j = 0; j < 4; j++)
      for (int r = 0; r < 4; r++) acc[i][j][r] = 0.f;

  int mrow = lane & 15, q = lane >> 4;

  for (int kk = 0; kk < K; kk += 32) {
    #pragma unroll
    for (int p = 0; p < 2; p++) {
      int idx = t + p * 256;
      int row = idx >> 2, ch = idx & 3;
      int brow = bn + row;
      if (brow >= nsrc) brow = 0;  // clamp; masked at store
      const float4* ap = (const float4*)&A[(size_t)(bm + row) * lda + kk + ch * 8];
      float4 a0 = ap[0], a1 = ap[1];
      const float4* bpp = (const float4*)&B[(size_t)brow * lda + kk + ch * 8];
      float4 b0 = bpp[0], b1 = bpp[1];
      union { u32 u[4]; uint4 v; } pa, pb;
      pa.u[0] = pkbf(a0.x, a0.y); pa.u[1] = pkbf(a0.z, a0.w);
      pa.u[2] = pkbf(a1.x, a1.y); pa.u[3] = pkbf(a1.z, a1.w);
      pb.u[0] = pkbf(b0.x, b0.y); pb.u[1] = pkbf(b0.z, b0.w);
      pb.u[2] = pkbf(b1.x, b1.y); pb.u[3] = pkbf(b1.z, b1.w);
      *(uint4*)&As[idx * 8] = pa.v;
      *(uint4*)&Bs[idx * 8] = pb.v;
    }
    __syncthreads();

    bf16x8 af[4], bfr[4];
    #pragma unroll
    for (int i = 0; i < 4; i++)
      af[i] = *(const bf16x8*)&As[(wm + i * 16 + mrow) * 32 + q * 8];
    #pragma unroll
    for (int j = 0; j < 4; j++)
      bfr[j] = *(const bf16x8*)&Bs[(wn + j * 16 + mrow) * 32 + q * 8];
    #pragma unroll
    for (int i = 0; i < 4; i++)
      #pragma unroll
      for (int j = 0; j < 4; j++)
        acc[i][j] = __builtin_amdgcn_mfma_f32_16x16x32_bf16(
            af[i], bfr[j], acc[i][j], 0, 0, 0);
    __syncthreads();
  }

  // epilogue: C/D layout col=lane&15, row=(lane>>4)*4+reg
  #pragma unroll
  for (int i = 0; i < 4; i++)
    #pragma unroll
    for (int j = 0; j < 4; j++) {
      int col = bn + wn + j * 16 + (lane & 15);
      int rb = bm + wm + i * 16 + (lane >> 4) * 4;
      #pragma unroll
      for (int r = 0; r < 4; r++) {
        int m = rb + r;
        if (col < 300) {
          float v = acc[i][j][r];
          v += bias[col] + wv[(size_t)label[m] * 300 + col];
          C[(size_t)m * 300 + col] = v;
          if (kemb16) kemb16[(size_t)m * 320 + col] = f2bu(v);
        } else if (kemb16 && col < 320) {
          kemb16[(size_t)m * 320 + col] = 0;
        }
      }
    }
}

// ---------------------------------------------------------------------------
// gemm0 v3: k_emb = feature @ Wf16^T + bf + wv[label]
//   - 64x128 tile, 4 waves (2x2), grid 768 (= 3 blocks/CU, vs 384 before)
//   - A staged RAW f32 via global_load_lds (prep_f16 pass deleted);
//     f32->bf16 cvt_pk on the LDS->reg fragment read (hidden under MFMA)
//   - 2-phase double-buffered pipeline: STAGE(next) issued BEFORE compute,
//     single __syncthreads (vmcnt0 drain) per iteration AFTER MFMA
//   - A-tile XOR swizzle (pre-swizzled global src + swizzled read, both-sides):
//     f32 rows are 128B = full bank period -> 16 lanes/bank-pos unswizzled
//   - XCD swizzle: the 3 N-blocks sharing an A-panel land adjacent on one
//     XCD -> 2/3 of the A re-read served by that XCD's L2
// ---------------------------------------------------------------------------
__global__ __launch_bounds__(256) void gemm0v3_kernel(
    const float* __restrict__ A, const u16* __restrict__ Bf16,
    const float* __restrict__ bias, const int* __restrict__ label,
    const float* __restrict__ wv, float* __restrict__ C,
    u16* __restrict__ kemb16)
{
  __shared__ __align__(16) float As[2][64 * 32];
  __shared__ __align__(16) u16  Bs[2][128 * 32];
  const int NIT = 64;                       // 2048 / 32
  int t = threadIdx.x;
  int g = blockIdx.x;
  int seq = (g & 7) * 96 + (g >> 3);        // XCD x gets seq [96x, 96x+96)
  int bm = (seq / 3) * 64;
  int bn = (seq % 3) * 128;
  int lane = t & 63, w = t >> 6;
  int wm = (w >> 1) * 32, wn = (w & 1) * 64;

  f32x4 acc[2][4];
  #pragma unroll
  for (int i = 0; i < 2; i++)
    #pragma unroll
    for (int j = 0; j < 4; j++)
      #pragma unroll
      for (int r = 0; r < 4; r++) acc[i][j][r] = 0.f;

  int mrow = lane & 15, q = lane >> 4;
  // staging geometry: A glds covers 8 rows x 32 f32 (lane -> row l/8, 16B
  // chunk l%8); B glds covers 16 rows x 32 bf16 (row l/4, 16B chunk l%4)
  int rlA = lane >> 3, chA = lane & 7;
  int rlB = lane >> 2, chB = lane & 3;
  int csA = (chA ^ rlA) * 4;                // source pre-swizzle (f32 cols)
  int csB = chB * 8;                        // B already at b128 bank floor

  const float* gA0 = &A[(size_t)(bm + w * 16 + rlA) * 2048 + csA];
  const float* gA1 = &A[(size_t)(bm + w * 16 + 8 + rlA) * 2048 + csA];
  const u16*   gB0 = &Bf16[(size_t)(bn + w * 32 + rlB) * 2048 + csB];
  const u16*   gB1 = &Bf16[(size_t)(bn + w * 32 + 16 + rlB) * 2048 + csB];

  auto STAGE = [&](int buf, int kk) {
    glds16f(gA0 + kk, &As[buf][(w * 16) * 32]);
    glds16f(gA1 + kk, &As[buf][(w * 16 + 8) * 32]);
    glds16(gB0 + kk, &Bs[buf][(w * 32) * 32]);
    glds16(gB1 + kk, &Bs[buf][(w * 32 + 16) * 32]);
  };

  STAGE(0, 0);
  __syncthreads();

  for (int it = 0; it < NIT; ++it) {
    int cur = it & 1;
    if (it + 1 < NIT) STAGE(cur ^ 1, (it + 1) * 32);   // loads fly over MFMA

    bf16x8 af[2], bfr[4];
    #pragma unroll
    for (int i = 0; i < 2; i++) {
      int r = wm + i * 16 + mrow;
      int c0 = ((q * 2) ^ (r & 7)) * 4;       // swizzled read (matches src)
      int c1 = ((q * 2 + 1) ^ (r & 7)) * 4;
      f32x4 x = *(const f32x4*)&As[cur][r * 32 + c0];
      f32x4 y = *(const f32x4*)&As[cur][r * 32 + c1];
      union { u32 u[4]; bf16x8 h; } cc;
      cc.u[0] = pkbf(x[0], x[1]); cc.u[1] = pkbf(x[2], x[3]);
      cc.u[2] = pkbf(y[0], y[1]); cc.u[3] = pkbf(y[2], y[3]);
      af[i] = cc.h;
    }
    #pragma unroll
    for (int j = 0; j < 4; j++)
      bfr[j] = *(const bf16x8*)&Bs[cur][(wn + j * 16 + mrow) * 32 + q * 8];
    #pragma unroll
    for (int i = 0; i < 2; i++)
      #pragma unroll
      for (int j = 0; j < 4; j++)
        acc[i][j] = __builtin_amdgcn_mfma_f32_16x16x32_bf16(
            af[i], bfr[j], acc[i][j], 0, 0, 0);

    __syncthreads();   // drains vmcnt(0): next tile staged; WAR on cur safe
  }

  // epilogue: C/D layout col=lane&15, row=(lane>>4)*4+reg
  #pragma unroll
  for (int i = 0; i < 2; i++)
    #pragma unroll
    for (int j = 0; j < 4; j++) {
      int col = bn + wn + j * 16 + (lane & 15);
      int rb = bm + wm + i * 16 + (lane >> 4) * 4;
      #pragma unroll
      for (int r = 0; r < 4; r++) {
        int m = rb + r;
        if (col < 300) {
          float v = acc[i][j][r] + bias[col] + wv[(size_t)label[m] * 300 + col];
          C[(size_t)m * 300 + col] = v;
          kemb16[(size_t)m * 320 + col] = f2bu(v);
        } else if (col < 320) {
          kemb16[(size_t)m * 320 + col] = 0;
        }
      }
    }
}

// ---------------------------------------------------------------------------
// attn (MFMA): block = (b, half of 16 y) -> 192 qwords x 64 keys, K=320.
// ke bf16 in LDS stride 344; A frags straight from wv16 (FULL) with depth-1
// prefetch, or from wv f32 (fallback). Softmax via shfl (1/sum-exp identity),
// word-softmax/5, vectorized p_raw -> praw bf16 [row][320].
// ---------------------------------------------------------------------------
#define KES 344
template <int FULL>
__global__ __launch_bounds__(256) void attn_kernel(
    const float* __restrict__ wv, const u16* __restrict__ wv16,
    const int* __restrict__ query,
    const float* __restrict__ kout, const u16* __restrict__ kemb16,
    u16* __restrict__ praw)
{
  __shared__ __align__(16) u16 ke[64 * KES];
  __shared__ __align__(16) int qoff[192];
  __shared__ __align__(16) float awd[192];
  __shared__ __align__(16) float wt[192];

  int blk = blockIdx.x, b = blk >> 1, bh = blk & 1;
  int t = threadIdx.x;
  int lane = t & 63, w = t >> 6;

  if (FULL) {
    for (int i = t; i < 2560; i += 256) {          // uint4 chunks of 8 cols
      int row = i / 40, ch = i % 40;
      *(uint4*)&ke[row * KES + ch * 8] =
          *(const uint4*)&kemb16[(size_t)(b * 64 + row) * 320 + ch * 8];
    }
  } else {
    for (int i = t; i < 4800; i += 256) {          // float4 chunks of 4 cols
      int row = i / 75, c4 = i % 75;
      float4 v = *(const float4*)&kout[(size_t)(b * 64 + row) * 300 + c4 * 4];
      *(u32*)&ke[row * KES + c4 * 4]     = pkbf(v.x, v.y);
      *(u32*)&ke[row * KES + c4 * 4 + 2] = pkbf(v.z, v.w);
    }
    for (int i = t; i < 640; i += 256) {           // zero cols 300..319
      int row = i / 10, c2 = i % 10;
      *(u32*)&ke[row * KES + 300 + c2 * 2] = 0;
    }
  }
  if (t < 192)
    qoff[t] = query[b * 384 + bh * 192 + t] * (FULL ? 320 : 300);
  __syncthreads();

  int mrow = lane & 15, q = lane >> 4;
  f32x4 acc[3][4];
  #pragma unroll
  for (int i = 0; i < 3; i++)
    #pragma unroll
    for (int j = 0; j < 4; j++)
      #pragma unroll
      for (int r = 0; r < 4; r++) acc[i][j][r] = 0.f;

  int base[3];
  #pragma unroll
  for (int i = 0; i < 3; i++) base[i] = qoff[w * 48 + i * 16 + mrow];
  int keb = mrow * KES + q * 8;

  bf16x8 afn[3];
  #pragma unroll
  for (int i = 0; i < 3; i++) {
    if (FULL)
      afn[i] = *(const bf16x8*)&wv16[(size_t)base[i] + q * 8];
  }

  for (int k0 = 0; k0 < 320; k0 += 32) {
    bf16x8 af[3], bfr[4];
    #pragma unroll
    for (int i = 0; i < 3; i++) {
      if (FULL) {
        af[i] = afn[i];
        if (k0 + 32 < 320)      // depth-1 prefetch
          afn[i] = *(const bf16x8*)&wv16[(size_t)base[i] + k0 + 32 + q * 8];
      } else {
        int cs = k0 + q * 8;
        union { u32 u[4]; bf16x8 h; } c;
        if (cs + 8 <= 300) {
          const float4* p = (const float4*)&wv[(size_t)base[i] + cs];
          float4 x = p[0], y = p[1];
          c.u[0] = pkbf(x.x, x.y); c.u[1] = pkbf(x.z, x.w);
          c.u[2] = pkbf(y.x, y.y); c.u[3] = pkbf(y.z, y.w);
        } else if (cs < 300) {   // cs == 296
          float4 x = *(const float4*)&wv[(size_t)base[i] + 296];
          c.u[0] = pkbf(x.x, x.y); c.u[1] = pkbf(x.z, x.w);
          c.u[2] = 0; c.u[3] = 0;
        } else {
          c.u[0] = 0; c.u[1] = 0; c.u[2] = 0; c.u[3] = 0;
        }
        af[i] = c.h;
      }
    }
    #pragma unroll
    for (int j = 0; j < 4; j++)
      bfr[j] = *(const bf16x8*)&ke[j * 16 * KES + keb + k0];
    #pragma unroll
    for (int i = 0; i < 3; i++)
      #pragma unroll
      for (int j = 0; j < 4; j++)
        acc[i][j] = __builtin_amdgcn_mfma_f32_16x16x32_bf16(
            af[i], bfr[j], acc[i][j], 0, 0, 0);
  }

  // per-word softmax-over-keys: a_w = 1/sum_k exp(scale*(att-max))
  const float scale = 0.05773502691896258f;   // 1/sqrt(300)
  #pragma unroll
  for (int i = 0; i < 3; i++)
    #pragma unroll
    for (int r = 0; r < 4; r++) {
      float mx = fmaxf(fmaxf(acc[i][0][r], acc[i][1][r]),
                       fmaxf(acc[i][2][r], acc[i][3][r]));
      #pragma unroll
      for (int d = 1; d < 16; d <<= 1)
        mx = fmaxf(mx, __shfl_xor(mx, d));
      float se = 0.f;
      #pragma unroll
      for (int j = 0; j < 4; j++)
        se += __expf((acc[i][j][r] - mx) * scale);
      #pragma unroll
      for (int d = 1; d < 16; d <<= 1)
        se += __shfl_xor(se, d);
      if (mrow == 0) {
        int wl = w * 48 + i * 16 + q * 4 + r;
        awd[wl] = (qoff[wl] == 0) ? -3.402823466e38f : (1.0f / se);
      }
    }
  __syncthreads();

  // per-y softmax over 12 words, /5
  if (t < 16) {
    int yb = t * 12;
    float m2 = -3.402823466e38f;
    for (int i = 0; i < 12; i++) m2 = fmaxf(m2, awd[yb + i]);
    float e[12], s2 = 0.f;
    for (int i = 0; i < 12; i++) { e[i] = __expf(awd[yb + i] - m2); s2 += e[i]; }
    float inv = 0.2f / s2;
    for (int i = 0; i < 12; i++) wt[yb + i] = e[i] * inv;
  }
  __syncthreads();

  // p_raw: wave w -> 4 y's
  #pragma unroll
  for (int yy = 0; yy < 4; yy++) {
    int yl = w * 4 + yy;
    int row = b * 32 + bh * 16 + yl;
    if (FULL) {
      if (lane < 40) {     // lane covers 8 cols; 40*8 = 320
        float s[8];
        #pragma unroll
        for (int e = 0; e < 8; e++) s[e] = 0.f;
        for (int i = 0; i < 12; i++) {
          float g = wt[yl * 12 + i];
          union { uint4 v; u16 h[8]; } qv;
          qv.v = *(const uint4*)&wv16[(size_t)qoff[yl * 12 + i] + lane * 8];
          #pragma unroll
          for (int e = 0; e < 8; e++) s[e] += g * b2f(qv.h[e]);
        }
        union { uint4 v; u16 h[8]; } o;
        #pragma unroll
        for (int e = 0; e < 8; e++) o.h[e] = f2bu(s[e]);
        *(uint4*)&praw[(size_t)row * 320 + lane * 8] = o.v;
      }
    } else {
      #pragma unroll
      for (int c = 0; c < 5; c++) {
        int d = c * 64 + lane;
        float s = 0.f;
        if (d < 300)
          for (int i = 0; i < 12; i++)
            s += wt[yl * 12 + i] * wv[(size_t)qoff[yl * 12 + i] + d];
        praw[(size_t)row * 320 + d] = f2bu(s);
      }
    }
  }
}

// ---------------------------------------------------------------------------
// proj (MFMA + glds): p_emb[8192][300] = praw(bf16) @ Wc(bf16)^T + bc -> f32
// ---------------------------------------------------------------------------
__global__ __launch_bounds__(256) void proj_kernel(
    const u16* __restrict__ praw, const u16* __restrict__ Wc,
    const float* __restrict__ bc, float* __restrict__ P)
{
  __shared__ __align__(16) u16 As[128 * 32];
  __shared__ __align__(16) u16 Bs[128 * 32];
  int t = threadIdx.x;
  int bm = (blockIdx.x / 3) * 128;
  int bn = (blockIdx.x % 3) * 128;
  int lane = t & 63, w = t >> 6;
  int wm = (w >> 1) * 64, wn = (w & 1) * 64;

  f32x4 acc[4][4];
  for (int i = 0; i < 4; i++)
    for (int j = 0; j < 4; j++)
      for (int r = 0; r < 4; r++) acc[i][j][r] = 0.f;

  int mrow = lane & 15, q = lane >> 4;

  for (int kk = 0; kk < 320; kk += 32) {
    int r0 = w * 32;
    int rl = lane >> 2, ch = lane & 3;
    #pragma unroll
    for (int p = 0; p < 2; p++) {
      int row = r0 + p * 16 + rl;
      glds16(&praw[(size_t)(bm + row) * 320 + kk + ch * 8],
             &As[(r0 + p * 16) * 32]);
      glds16(&Wc[(size_t)(bn + row) * 320 + kk + ch * 8],
             &Bs[(r0 + p * 16) * 32]);
    }
    __syncthreads();

    bf16x8 af[4], bfr[4];
    #pragma unroll
    for (int i = 0; i < 4; i++)
      af[i] = *(const bf16x8*)&As[(wm + i * 16 + mrow) * 32 + q * 8];
    #pragma unroll
    for (int j = 0; j < 4; j++)
      bfr[j] = *(const bf16x8*)&Bs[(wn + j * 16 + mrow) * 32 + q * 8];
    #pragma unroll
    for (int i = 0; i < 4; i++)
      #pragma unroll
      for (int j = 0; j < 4; j++)
        acc[i][j] = __builtin_amdgcn_mfma_f32_16x16x32_bf16(
            af[i], bfr[j], acc[i][j], 0, 0, 0);
    __syncthreads();
  }

  #pragma unroll
  for (int i = 0; i < 4; i++)
    #pragma unroll
    for (int j = 0; j < 4; j++) {
      int col = bn + wn + j * 16 + (lane & 15);
      if (col >= 300) continue;
      int rb = bm + wm + i * 16 + (lane >> 4) * 4;
      #pragma unroll
      for (int r = 0; r < 4; r++)
        P[(size_t)(rb + r) * 300 + col] = acc[i][j][r] + bc[col];
    }
}

// ---------------------------------------------------------------------------
extern "C" void kernel_launch(void* const* d_in, const int* in_sizes, int n_in,
                              void* d_out, int out_size, void* d_ws,
                              size_t ws_size, hipStream_t stream)
{
  const float* wv      = (const float*)d_in[0];   // [30000,300] f32
  const float* Wf      = (const float*)d_in[1];   // [300,2048]  f32
  const float* bf      = (const float*)d_in[2];   // [300]       f32
  const float* Wp      = (const float*)d_in[3];   // [300,300]   f32
  const float* bp      = (const float*)d_in[4];   // [300]       f32
  const float* Wm      = (const float*)d_in[5];   // [300,300]   f32
  const float* bm      = (const float*)d_in[6];   // [300]       f32
  const float* feature = (const float*)d_in[7];   // [256,64,2048] f32
  const int*   query   = (const int*)d_in[8];     // [256,32,12]
  const int*   label   = (const int*)d_in[9];     // [256,64]

  float* out   = (float*)d_out;     // f32 output
  float* p_out = out;               // p_emb: 8192*300
  float* k_out = out + 2457600;     // k_emb: 16384*300

  char* ws = (char*)d_ws;
  // T2 layout (feature16 slot now unused - gemm0v3 stages f32 directly):
  //   (unused):           0  (67,108,864)
  //   wv16:      67,108,864  (19,200,000)
  //   kemb16:    86,308,864  (10,485,760)
  //   praw:      96,794,624  ( 5,242,880)
  //   Wc:       102,037,504  (   245,760)
  //   Wf16:     102,283,264  ( 1,572,864)
  //   bc:       103,856,128  (     1,536)
  int t2 = ws_size >= (size_t)103857664;
  int t1 = ws_size >= (size_t)35175936;
  u16 *wf16 = 0, *wv16 = 0, *kemb16 = 0, *praw, *Wc;
  float* bc;
  if (t2) {
    wv16   = (u16*)(ws + 67108864);
    kemb16 = (u16*)(ws + 86308864);
    praw   = (u16*)(ws + 96794624);
    Wc     = (u16*)(ws + 102037504);
    wf16   = (u16*)(ws + 102283264);
    bc     = (float*)(ws + 103856128);
  } else if (t1) {
    wv16   = (u16*)ws;                    // 19,200,000
    kemb16 = (u16*)(ws + 19200000);       // 10,485,760
    praw   = (u16*)(ws + 29685760);       //  5,242,880
    Wc     = (u16*)(ws + 34928640);       //    245,760
    bc     = (float*)(ws + 35174400);
  } else {
    praw   = (u16*)ws;
    Wc     = (u16*)(ws + 5242880);
    bc     = (float*)(ws + 5488640);
  }

  prep_wc<<<240, 256, 0, stream>>>(Wp, bp, Wm, bm, Wc, bc);
  if (t1 || t2)
    prep_wv16<<<18750, 256, 0, stream>>>(wv, wv16);
  if (t2) {
    prep_wf16<<<1536, 256, 0, stream>>>(Wf, wf16);
    gemm0v3_kernel<<<768, 256, 0, stream>>>(feature, wf16, bf,
                                            label, wv, k_out, kemb16);
  } else {
    gemm0_kernel<0><<<384, 256, 0, stream>>>(feature, Wf, 0, 0, bf,
                                             label, wv, k_out, kemb16);
  }

  if (t1 || t2)
    attn_kernel<1><<<512, 256, 0, stream>>>(wv, wv16, query, k_out,
                                            kemb16, praw);
  else
    attn_kernel<0><<<512, 256, 0, stream>>>(wv, wv16, query, k_out,
                                            kemb16, praw);

  proj_kernel<<<192, 256, 0, stream>>>(praw, Wc, bc, p_out);
}